// Round 1
// baseline (587.526 us; speedup 1.0000x reference)
//
#include <hip/hip_runtime.h>

typedef _Float16 half8 __attribute__((ext_vector_type(8)));
typedef float floatx4 __attribute__((ext_vector_type(4)));

#define DDIM 64
#define LN_EPS 1e-5f
#define SHIFT 20.0f

#define RB 128   // rows per block (of B=512)
#define CK 64    // cols per chunk iteration
#define CPB 8    // chunks per block
#define STR 72   // LDS row stride in f16 elems (144 B: 16B-aligned, 2-way bank alias = free)

__device__ inline float wave_sum(float v) {
#pragma unroll
  for (int m = 1; m < 64; m <<= 1) v += __shfl_xor(v, m, 64);
  return v;
}

// LayerNorm both tables, emit f16 hi/lo split planes. One wave per row.
__global__ __launch_bounds__(256) void ln_kernel(
    const float* __restrict__ Eo, const float* __restrict__ Ed,
    const float* __restrict__ go, const float* __restrict__ bo,
    const float* __restrict__ gd, const float* __restrict__ bd,
    _Float16* __restrict__ Co_hi, _Float16* __restrict__ Co_lo,
    _Float16* __restrict__ Cd_hi, _Float16* __restrict__ Cd_lo, int N) {
  int row = blockIdx.x * 4 + (threadIdx.x >> 6);
  if (row >= N) return;
  int lane = threadIdx.x & 63;
  size_t idx = (size_t)row * DDIM + lane;
  {
    float x = Eo[idx];
    float m = wave_sum(x) * (1.0f / DDIM);
    float d = x - m;
    float var = wave_sum(d * d) * (1.0f / DDIM);
    float y = d * rsqrtf(var + LN_EPS) * go[lane] + bo[lane];
    _Float16 hi = (_Float16)y;
    Co_hi[idx] = hi;
    Co_lo[idx] = (_Float16)(y - (float)hi);
  }
  {
    float x = Ed[idx];
    float m = wave_sum(x) * (1.0f / DDIM);
    float d = x - m;
    float var = wave_sum(d * d) * (1.0f / DDIM);
    float y = d * rsqrtf(var + LN_EPS) * gd[lane] + bd[lane];
    _Float16 hi = (_Float16)y;
    Cd_hi[idx] = hi;
    Cd_lo[idx] = (_Float16)(y - (float)hi);
  }
}

// PASS 0: accumulate sum of exp(score - SHIFT) per row into sums[] (atomics).
// PASS 1: write out exp(score - SHIFT) / sum.
// Scores via split-f16 MFMA: s = qh*ch + qh*cl + ql*ch (ql*cl dropped, ~2^-22).
template <int PASS>
__global__ __launch_bounds__(256, 2) void score_kernel(
    const _Float16* __restrict__ Co_hi, const _Float16* __restrict__ Co_lo,
    const _Float16* __restrict__ Cd_hi, const _Float16* __restrict__ Cd_lo,
    const int* __restrict__ ids, float* __restrict__ sums,
    float* __restrict__ out, int N, int B) {
  __shared__ __attribute__((aligned(16))) _Float16 Qh[RB * STR];
  __shared__ __attribute__((aligned(16))) _Float16 Ql[RB * STR];
  __shared__ __attribute__((aligned(16))) _Float16 Ch[CK * STR];
  __shared__ __attribute__((aligned(16))) _Float16 Cl[CK * STR];
  __shared__ float inv_lds[RB];

  const int t = threadIdx.x;
  const int mat = blockIdx.z;
  const int mbase = blockIdx.y * RB;
  const _Float16* Qsrc_h = (mat == 0) ? Co_hi : Cd_hi;
  const _Float16* Qsrc_l = (mat == 0) ? Co_lo : Cd_lo;
  const _Float16* Csrc_h = (mat == 0) ? Cd_hi : Co_hi;
  const _Float16* Csrc_l = (mat == 0) ? Cd_lo : Co_lo;

  // Stage Q (gathered rows) into LDS: per plane 128 rows * 128 B.
#pragma unroll
  for (int rnd = 0; rnd < 4; ++rnd) {
    int f = (rnd * 256 + t) * 16;  // byte offset within plane image (row-major, 128B rows)
    int r = f >> 7;
    int off = f & 127;
    int id = ids[mbase + r];
    *(uint4*)((char*)Qh + r * (STR * 2) + off) =
        *(const uint4*)((const char*)Qsrc_h + (size_t)id * 128 + off);
    *(uint4*)((char*)Ql + r * (STR * 2) + off) =
        *(const uint4*)((const char*)Qsrc_l + (size_t)id * 128 + off);
  }
  if (PASS == 1) {
    if (t < RB) inv_lds[t] = 1.0f / sums[(size_t)mat * B + mbase + t];
  }
  __syncthreads();

  const int lane = t & 63;
  const int wv = t >> 6;
  const int l15 = lane & 15;
  const int quad = lane >> 4;

  // A fragments (persistent in registers): wave handles m-tiles {2wv, 2wv+1}
  half8 Ah[2][2], Al[2][2];
#pragma unroll
  for (int mt = 0; mt < 2; ++mt) {
    int r = wv * 32 + mt * 16 + l15;
    int e0 = r * STR + quad * 8;
    Ah[mt][0] = *(const half8*)&Qh[e0];
    Ah[mt][1] = *(const half8*)&Qh[e0 + 32];
    Al[mt][0] = *(const half8*)&Ql[e0];
    Al[mt][1] = *(const half8*)&Ql[e0 + 32];
  }

  float sumacc[2][4];
  if (PASS == 0) {
#pragma unroll
    for (int mt = 0; mt < 2; ++mt)
#pragma unroll
      for (int r = 0; r < 4; ++r) sumacc[mt][r] = 0.0f;
  }

  const int nc_total = (N + CK - 1) / CK;
  const int c0 = blockIdx.x * CPB;
  for (int ic = 0; ic < CPB; ++ic) {
    int chunk = c0 + ic;
    if (chunk >= nc_total) break;
    int nbase = chunk * CK;
    __syncthreads();  // previous iteration's reads of Ch/Cl done
#pragma unroll
    for (int rnd = 0; rnd < 2; ++rnd) {
      int f = (rnd * 256 + t) * 16;
      int r = f >> 7;
      int off = f & 127;
      int grow = nbase + r;
      if (grow < N) {
        *(uint4*)((char*)Ch + r * (STR * 2) + off) =
            *(const uint4*)((const char*)Csrc_h + (size_t)grow * 128 + off);
        *(uint4*)((char*)Cl + r * (STR * 2) + off) =
            *(const uint4*)((const char*)Csrc_l + (size_t)grow * 128 + off);
      } else {
        uint4 z = {0, 0, 0, 0};
        *(uint4*)((char*)Ch + r * (STR * 2) + off) = z;
        *(uint4*)((char*)Cl + r * (STR * 2) + off) = z;
      }
    }
    __syncthreads();

#pragma unroll
    for (int nt = 0; nt < 4; ++nt) {
      int cr = nt * 16 + l15;
      int e0 = cr * STR + quad * 8;
      half8 Bh0 = *(const half8*)&Ch[e0];
      half8 Bh1 = *(const half8*)&Ch[e0 + 32];
      half8 Bl0 = *(const half8*)&Cl[e0];
      half8 Bl1 = *(const half8*)&Cl[e0 + 32];
      int col = nbase + nt * 16 + l15;
      bool valid = col < N;
#pragma unroll
      for (int mt = 0; mt < 2; ++mt) {
        floatx4 acc = {0.0f, 0.0f, 0.0f, 0.0f};
        acc = __builtin_amdgcn_mfma_f32_16x16x32_f16(Ah[mt][0], Bh0, acc, 0, 0, 0);
        acc = __builtin_amdgcn_mfma_f32_16x16x32_f16(Ah[mt][1], Bh1, acc, 0, 0, 0);
        acc = __builtin_amdgcn_mfma_f32_16x16x32_f16(Ah[mt][0], Bl0, acc, 0, 0, 0);
        acc = __builtin_amdgcn_mfma_f32_16x16x32_f16(Ah[mt][1], Bl1, acc, 0, 0, 0);
        acc = __builtin_amdgcn_mfma_f32_16x16x32_f16(Al[mt][0], Bh0, acc, 0, 0, 0);
        acc = __builtin_amdgcn_mfma_f32_16x16x32_f16(Al[mt][1], Bh1, acc, 0, 0, 0);
#pragma unroll
        for (int r = 0; r < 4; ++r) {
          float p = __expf(acc[r] - SHIFT);
          if (PASS == 0) {
            sumacc[mt][r] += valid ? p : 0.0f;
          } else if (valid) {
            int rl = wv * 32 + mt * 16 + quad * 4 + r;
            int b = mbase + rl;
            out[(size_t)mat * B * N + (size_t)b * N + col] = p * inv_lds[rl];
          }
        }
      }
    }
  }

  if (PASS == 0) {
#pragma unroll
    for (int mt = 0; mt < 2; ++mt)
#pragma unroll
      for (int r = 0; r < 4; ++r) {
        float v = sumacc[mt][r];
        v += __shfl_xor(v, 1, 64);
        v += __shfl_xor(v, 2, 64);
        v += __shfl_xor(v, 4, 64);
        v += __shfl_xor(v, 8, 64);
        if (l15 == 0) {
          int rl = wv * 32 + mt * 16 + quad * 4 + r;
          atomicAdd(&sums[(size_t)mat * B + mbase + rl], v);
        }
      }
  }
}

extern "C" void kernel_launch(void* const* d_in, const int* in_sizes, int n_in,
                              void* d_out, int out_size, void* d_ws, size_t ws_size,
                              hipStream_t stream) {
  const int* ids = (const int*)d_in[0];
  const float* Eo = (const float*)d_in[1];
  const float* Ed = (const float*)d_in[2];
  const float* go = (const float*)d_in[3];
  const float* bo = (const float*)d_in[4];
  const float* gd = (const float*)d_in[5];
  const float* bd = (const float*)d_in[6];
  const int B = in_sizes[0];          // 512
  const int N = in_sizes[1] / DDIM;   // 100000
  float* out = (float*)d_out;

  char* ws = (char*)d_ws;
  size_t plane = (size_t)N * DDIM * sizeof(_Float16);  // 12.8 MB
  _Float16* Co_hi = (_Float16*)(ws + 0 * plane);
  _Float16* Co_lo = (_Float16*)(ws + 1 * plane);
  _Float16* Cd_hi = (_Float16*)(ws + 2 * plane);
  _Float16* Cd_lo = (_Float16*)(ws + 3 * plane);
  float* sums = (float*)(ws + 4 * plane);  // 2*B floats

  hipMemsetAsync(sums, 0, (size_t)2 * B * sizeof(float), stream);

  ln_kernel<<<(N + 3) / 4, 256, 0, stream>>>(Eo, Ed, go, bo, gd, bd,
                                             Co_hi, Co_lo, Cd_hi, Cd_lo, N);

  int nc_total = (N + CK - 1) / CK;            // 1563
  int gx = (nc_total + CPB - 1) / CPB;         // 196
  dim3 grid(gx, B / RB, 2);
  score_kernel<0><<<grid, 256, 0, stream>>>(Co_hi, Co_lo, Cd_hi, Cd_lo, ids,
                                            sums, out, N, B);
  score_kernel<1><<<grid, 256, 0, stream>>>(Co_hi, Co_lo, Cd_hi, Cd_lo, ids,
                                            sums, out, N, B);
}